// Round 7
// baseline (524.065 us; speedup 1.0000x reference)
//
#include <hip/hip_runtime.h>
#include <math.h>

#define NQ    40000
#define EDIM  256
#define BEVH  200
#define BEVW  200

enum { A_IM2COL = 0, A_VAL = 1, A_PLAIN = 2 };
enum { OUT_F32 = 0, OUT_VSLAB = 1, OUT_CONV = 2, OUT_F32ADD = 3 };

typedef __attribute__((ext_vector_type(8))) short bf16x8;
typedef __attribute__((ext_vector_type(4))) short bf16x4;
typedef __attribute__((ext_vector_type(4))) float f32x4;

typedef __attribute__((address_space(3))) unsigned int lds_u32_t;
typedef const __attribute__((address_space(1))) unsigned int g_u32_t;
#define GLOAD_LDS16(g, l) __builtin_amdgcn_global_load_lds((g_u32_t*)(g), (lds_u32_t*)(l), 16, 0, 0)

template <int N> __device__ __forceinline__ void vmwait() {
  if constexpr (N == 0) asm volatile("s_waitcnt vmcnt(0)" ::: "memory");
  else if constexpr (N == 6) asm volatile("s_waitcnt vmcnt(6)" ::: "memory");
  else if constexpr (N == 8) asm volatile("s_waitcnt vmcnt(8)" ::: "memory");
  else static_assert(N == 0 || N == 6 || N == 8, "add vmcnt case");
}

__device__ __forceinline__ short f2bf(float f) {
  union { float f; unsigned u; } uu; uu.f = f;
  unsigned r = (uu.u + 0x7fff + ((uu.u >> 16) & 1)) >> 16;
  return (short)r;
}
__device__ __forceinline__ float bf2f(short s) {
  union { unsigned u; float f; } v;
  v.u = ((unsigned)(unsigned short)s) << 16;
  return v.f;
}

// ---------------------------------------------------------------------------
// pad_kernel: zero-padded bf16 image img[203][202][512]; image (y,x) at padded
// (y+1,x+1). c<256 -> pre (= sos ? query : prebev); c>=256 -> query+qpos.
// Also writes qbf[n][0:256] = bf16(query).
// ---------------------------------------------------------------------------
__global__ __launch_bounds__(256) void pad_kernel(
    const float* __restrict__ query, const float* __restrict__ qpos,
    const float* __restrict__ prebev, const unsigned char* __restrict__ sos,
    short* __restrict__ img, short* __restrict__ qbf)
{
  const int TOT = 203 * 202 * 64;
  int t = blockIdx.x * 256 + threadIdx.x;
  if (t >= TOT) return;
  int s = t * 8;
  int pr = s / (202 * 512);
  int rem = s - pr * (202 * 512);
  int px = rem >> 9;
  int c = rem & 511;
  int y = pr - 1, x = px - 1;

  bf16x8 o;
#pragma unroll
  for (int j = 0; j < 8; j++) o[j] = 0;

  if (y >= 0 && y < BEVH && x >= 0 && x < BEVW) {
    int n = y * BEVW + x;
    if (c < 256) {
      bool sf = sos[0] != 0;
      const float* p = (sf ? query : prebev) + (size_t)n * 256 + c;
      float4 v0 = *(const float4*)p;
      float4 v1 = *(const float4*)(p + 4);
      o[0] = f2bf(v0.x); o[1] = f2bf(v0.y); o[2] = f2bf(v0.z); o[3] = f2bf(v0.w);
      o[4] = f2bf(v1.x); o[5] = f2bf(v1.y); o[6] = f2bf(v1.z); o[7] = f2bf(v1.w);
    } else {
      const float* pq = query + (size_t)n * 256 + (c - 256);
      const float* pp = qpos + (size_t)n * 256 + (c - 256);
      float4 q0 = *(const float4*)pq, q1 = *(const float4*)(pq + 4);
      float4 p0 = *(const float4*)pp, p1 = *(const float4*)(pp + 4);
      bf16x8 qo;
      qo[0] = f2bf(q0.x); qo[1] = f2bf(q0.y); qo[2] = f2bf(q0.z); qo[3] = f2bf(q0.w);
      qo[4] = f2bf(q1.x); qo[5] = f2bf(q1.y); qo[6] = f2bf(q1.z); qo[7] = f2bf(q1.w);
      *(bf16x8*)&qbf[(size_t)n * 256 + (c - 256)] = qo;
      o[0] = f2bf(q0.x + p0.x); o[1] = f2bf(q0.y + p0.y);
      o[2] = f2bf(q0.z + p0.z); o[3] = f2bf(q0.w + p0.w);
      o[4] = f2bf(q1.x + p1.x); o[5] = f2bf(q1.y + p1.y);
      o[6] = f2bf(q1.z + p1.z); o[7] = f2bf(q1.w + p1.w);
    }
  }
  *(bf16x8*)&img[s] = o;
}

// ---------------------------------------------------------------------------
// conv weights (co,ci,ky,kx) fp32 -> concat [192][tap*512+ci] bf16 + bias cat
// ---------------------------------------------------------------------------
__global__ __launch_bounds__(256) void reorder_cat_kernel(
    const float* __restrict__ off_w, const float* __restrict__ off_b,
    const float* __restrict__ attn_w, const float* __restrict__ attn_b,
    short* __restrict__ wcat, float* __restrict__ bcat)
{
  int i = blockIdx.x * 256 + threadIdx.x;
  if (i < 192) bcat[i] = i < 128 ? off_b[i] : attn_b[i - 128];
  if (i >= 192 * 4608) return;
  int co = i / 4608;
  int r = i - co * 4608;
  int tap = r >> 9, ci = r & 511;
  float v = co < 128 ? off_w[(size_t)co * 4608 + ci * 9 + tap]
                     : attn_w[(size_t)(co - 128) * 4608 + ci * 9 + tap];
  wcat[i] = f2bf(v);
}

__global__ __launch_bounds__(256) void wcast_kernel(
    const float* __restrict__ Wv, const float* __restrict__ Wo,
    short* __restrict__ wvb, short* __restrict__ wob)
{
  int t = blockIdx.x * 256 + threadIdx.x;
  if (t >= 16384) return;
  const float* src = t < 8192 ? Wv + (size_t)t * 8 : Wo + (size_t)(t - 8192) * 8;
  short* dst = t < 8192 ? wvb + (size_t)t * 8 : wob + (size_t)(t - 8192) * 8;
  float4 v0 = *(const float4*)src, v1 = *(const float4*)(src + 4);
  bf16x8 o;
  o[0] = f2bf(v0.x); o[1] = f2bf(v0.y); o[2] = f2bf(v0.z); o[3] = f2bf(v0.w);
  o[4] = f2bf(v1.x); o[5] = f2bf(v1.y); o[6] = f2bf(v1.z); o[7] = f2bf(v1.w);
  *(bf16x8*)dst = o;
}

// ---------------------------------------------------------------------------
// Unified bf16 MFMA GEMM: C[m][co] = sum_k A[m][k]*B[co][k] + bias[co]
// TBM x TBN tile, BK=64; 256 threads = 4 waves (2x2); wave tile TBM/2 x TBN/2.
// 2-phase double-buffered K-loop (T3-minimum): stage tile t+1 via
// global_load_lds, counted s_waitcnt vmcnt(ISS) (never 0 mid-loop) + raw
// s_barrier, compute tile t, barrier. Loads for t+1 stay in flight across MFMA.
// ---------------------------------------------------------------------------
template <int AMODE, int KTOT, int TBM, int TBN, int OUTMODE>
__global__ __launch_bounds__(256) void mfma_gemm_kernel(
    const short* __restrict__ A0, const short* __restrict__ A1,
    const short* __restrict__ Bw, const float* __restrict__ bias,
    const float* __restrict__ addend,
    float* __restrict__ Cf, short* __restrict__ Cb, int M)
{
  constexpr int A_ISS = TBM / 32;
  constexpr int B_ISS = TBN / 32;
  constexpr int ISS = A_ISS + B_ISS;
  constexpr int MR = TBM / 32;     // frags per wave in M (wave M = TBM/2)
  constexpr int NR = TBN / 32;
  constexpr int NT = KTOT / 64;

  __shared__ __align__(16) short As[2][TBM * 64];
  __shared__ __align__(16) short Bs[2][TBN * 64];

  const int tid = threadIdx.x;
  const int wv = tid >> 6, lane = tid & 63;
  const int wr_ = wv >> 1, wc = wv & 1;

  int bx = blockIdx.x;
  if constexpr (AMODE == A_IM2COL) {
    // bijective XCD-chunk swizzle for grid 625 (q=78, r=1): vertical-neighbor
    // strips share image rows -> keep them on the same XCD's L2.
    int xcd = bx & 7, pos = bx >> 3;
    bx = (xcd < 1 ? xcd * 79 : 79 + (xcd - 1) * 78) + pos;
  }
  const int m0 = bx * TBM;
  const int n0 = blockIdx.y * TBN;

  // swizzle: LDS chunk j of row r holds global chunk j ^ (r & 7)
  const int csw = ((lane & 7) ^ ((lane >> 3) & 7)) * 8;

  const short* ap[A_ISS];
#pragma unroll
  for (int i = 0; i < A_ISS; i++) {
    int m = m0 + (i * 4 + wv) * 8 + (lane >> 3);
    if constexpr (AMODE == A_IM2COL) {
      int y = m / BEVW;
      int x = m - y * BEVW;
      ap[i] = A0 + ((size_t)y * 202 + x) * 512 + csw;   // + tap offset per K-tile
    } else if constexpr (AMODE == A_VAL) {
      if (m < NQ) {
        int y = m / BEVW;
        int x = m - y * BEVW;
        ap[i] = A0 + ((size_t)(y + 1) * 202 + (x + 1)) * 512 + csw;
      } else {
        ap[i] = A1 + (size_t)(m - NQ) * 256 + csw;
      }
    } else {
      int mc = m < M ? m : M - 1;
      ap[i] = A0 + (size_t)mc * KTOT + csw;
    }
  }
  const short* bp[B_ISS];
#pragma unroll
  for (int i = 0; i < B_ISS; i++) {
    int r = n0 + (i * 4 + wv) * 8 + (lane >> 3);
    bp[i] = Bw + (size_t)r * KTOT + csw;
  }

  auto koff_of = [&](int t) -> int {
    if constexpr (AMODE == A_IM2COL) {
      int k0 = t * 64;
      int tap = k0 >> 9, c0 = k0 & 511;
      int ty = tap / 3, txp = tap - ty * 3;
      return (ty * 202 + txp) * 512 + c0;
    } else {
      return t * 64;
    }
  };

  auto stage = [&](int buf, int t) {
    int koff = koff_of(t);
    short* Ab = &As[buf][0];
    short* Bb = &Bs[buf][0];
#pragma unroll
    for (int i = 0; i < A_ISS; i++)
      GLOAD_LDS16(ap[i] + koff, Ab + (i * 4 + wv) * 512);
    int k0 = t * 64;
#pragma unroll
    for (int i = 0; i < B_ISS; i++)
      GLOAD_LDS16(bp[i] + k0, Bb + (i * 4 + wv) * 512);
  };

  f32x4 acc[MR][NR];
#pragma unroll
  for (int mr = 0; mr < MR; mr++)
#pragma unroll
    for (int nr = 0; nr < NR; nr++) acc[mr][nr] = (f32x4){0.f, 0.f, 0.f, 0.f};

  stage(0, 0);

  for (int t = 0; t < NT; ++t) {
    const int cur = t & 1;
    if (t + 1 < NT) {
      stage(cur ^ 1, t + 1);
      vmwait<ISS>();            // own tile-t loads done; t+1 stays in flight
    } else {
      vmwait<0>();
    }
    __builtin_amdgcn_s_barrier();
    __builtin_amdgcn_sched_barrier(0);

    const short* Ab = &As[cur][0];
    const short* Bb = &Bs[cur][0];
#pragma unroll
    for (int ks = 0; ks < 2; ks++) {
      const int kk = ks * 32 + (lane >> 4) * 8;
      bf16x8 af[MR], bfr[NR];
#pragma unroll
      for (int mr = 0; mr < MR; mr++) {
        int row = wr_ * (TBM / 2) + mr * 16 + (lane & 15);
        af[mr] = *(const bf16x8*)&Ab[row * 64 + (kk ^ ((row & 7) << 3))];
      }
#pragma unroll
      for (int nr = 0; nr < NR; nr++) {
        int row = wc * (TBN / 2) + nr * 16 + (lane & 15);
        bfr[nr] = *(const bf16x8*)&Bb[row * 64 + (kk ^ ((row & 7) << 3))];
      }
#pragma unroll
      for (int mr = 0; mr < MR; mr++)
#pragma unroll
        for (int nr = 0; nr < NR; nr++)
          acc[mr][nr] = __builtin_amdgcn_mfma_f32_16x16x32_bf16(
              af[mr], bfr[nr], acc[mr][nr], 0, 0, 0);
    }
    __builtin_amdgcn_sched_barrier(0);
    __builtin_amdgcn_s_barrier();   // protect buf[cur] before t+1 overwrites it
  }

  // epilogue: C/D layout col=lane&15, row=(lane>>4)*4+reg
#pragma unroll
  for (int mr = 0; mr < MR; mr++) {
#pragma unroll
    for (int nr = 0; nr < NR; nr++) {
      int col = n0 + wc * (TBN / 2) + nr * 16 + (lane & 15);
      float bsv = bias[col];
#pragma unroll
      for (int r = 0; r < 4; r++) {
        int grow = m0 + wr_ * (TBM / 2) + mr * 16 + (lane >> 4) * 4 + r;
        if (grow < M) {
          float o = acc[mr][nr][r] + bsv;
          if constexpr (OUTMODE == OUT_VSLAB) {
            int b = grow >= NQ;
            int n = grow - (b ? NQ : 0);
            int hh = col >> 5, d = col & 31;
            Cb[((size_t)(hh * 2 + b) * NQ + n) * 32 + d] = f2bf(o);
          } else if constexpr (OUTMODE == OUT_CONV) {
            int hh, j;
            if (col < 128) { hh = col >> 4; j = col & 15; }
            else { int c = col - 128; hh = c >> 3; j = 16 + (c & 7); }
            Cf[((size_t)hh * NQ + grow) * 24 + j] = o;
          } else if constexpr (OUTMODE == OUT_F32ADD) {
            o += addend[(size_t)grow * 256 + col];
            Cf[(size_t)grow * 256 + col] = o;
          } else {
            Cf[(size_t)grow * 256 + col] = o;
          }
        }
      }
    }
  }
}

// ---------------------------------------------------------------------------
// sample v3: blockIdx = q*8 + h  (h pins the block's XCD via id%8 heuristic:
// each XCD's random gathers touch only head h's 5.1 MB valp slab -> L2-hot).
// Wave: 8 queries x 8 lanes; lane g covers channels g*4..g*4+3 of head h.
// convall: [h][n][24] = {offsets b0 (8), offsets b1 (8), logits b0 (4), b1 (4)}
// valpb:   [(h*2+b)][n][32]
// ---------------------------------------------------------------------------
__global__ __launch_bounds__(256) void sample_kernel(
    const short* __restrict__ valpb, const float* __restrict__ convall,
    const float* __restrict__ preref, const float* __restrict__ refp,
    short* __restrict__ midb)
{
  int id = blockIdx.x;
  int h = id & 7, q = id >> 3;
  int wv = threadIdx.x >> 6, lane = threadIdx.x & 63;
  int n = q * 32 + wv * 8 + (lane >> 3);
  int g = lane & 7;

  const float* cv = convall + ((size_t)h * NQ + n) * 24;
  f32x4 acc = (f32x4){0.f, 0.f, 0.f, 0.f};

#pragma unroll
  for (int b = 0; b < 2; b++) {
    const float* rp = b ? refp : preref;
    float rx = rp[(size_t)n * 2 + 0] * 200.f - 0.5f;
    float ry = rp[(size_t)n * 2 + 1] * 200.f - 0.5f;

    float4 o01 = *(const float4*)(cv + b * 8);
    float4 o23 = *(const float4*)(cv + b * 8 + 4);
    float ox[4] = {o01.x, o01.z, o23.x, o23.z};
    float oy[4] = {o01.y, o01.w, o23.y, o23.w};

    float4 a = *(const float4*)(cv + 16 + b * 4);
    float mx = fmaxf(fmaxf(a.x, a.y), fmaxf(a.z, a.w));
    float e0 = __expf(a.x - mx), e1 = __expf(a.y - mx);
    float e2 = __expf(a.z - mx), e3 = __expf(a.w - mx);
    float inv = 1.f / (e0 + e1 + e2 + e3);
    float aw[4] = {e0 * inv, e1 * inv, e2 * inv, e3 * inv};

    const short* vb = valpb + ((size_t)(h * 2 + b) * NQ) * 32 + g * 4;

#pragma unroll
    for (int p = 0; p < 4; p++) {
      float x = rx + ox[p];
      float y = ry + oy[p];
      float x0f = floorf(x), y0f = floorf(y);
      float fx = x - x0f, fy = y - y0f;
      int x0 = (int)x0f, y0 = (int)y0f;
      float wt[4] = {(1.f - fx) * (1.f - fy), fx * (1.f - fy),
                     (1.f - fx) * fy, fx * fy};
      int xs[4] = {x0, x0 + 1, x0, x0 + 1};
      int ys[4] = {y0, y0, y0 + 1, y0 + 1};
#pragma unroll
      for (int c = 0; c < 4; c++) {
        if (xs[c] >= 0 && xs[c] < BEVW && ys[c] >= 0 && ys[c] < BEVH) {
          bf16x4 v = *(const bf16x4*)&vb[(size_t)(ys[c] * BEVW + xs[c]) * 32];
          float cw = aw[p] * wt[c];
          acc[0] += cw * bf2f(v[0]);
          acc[1] += cw * bf2f(v[1]);
          acc[2] += cw * bf2f(v[2]);
          acc[3] += cw * bf2f(v[3]);
        }
      }
    }
  }

  bf16x4 m4;
#pragma unroll
  for (int j = 0; j < 4; j++) m4[j] = f2bf(acc[j] * 0.5f);
  *(bf16x4*)&midb[(size_t)n * 256 + h * 32 + g * 4] = m4;
}

// ---------------------------------------------------------------------------
extern "C" void kernel_launch(void* const* d_in, const int* in_sizes, int n_in,
                              void* d_out, int out_size, void* d_ws, size_t ws_size,
                              hipStream_t stream)
{
  const float* query  = (const float*)d_in[0];
  const float* qpos   = (const float*)d_in[3];
  const float* refp   = (const float*)d_in[4];
  const float* prebev = (const float*)d_in[7];
  const float* preref = (const float*)d_in[8];
  const unsigned char* sos = (const unsigned char*)d_in[9];
  const float* Wv     = (const float*)d_in[10];
  const float* bv     = (const float*)d_in[11];
  const float* Wo     = (const float*)d_in[12];
  const float* bo     = (const float*)d_in[13];
  const float* off_w  = (const float*)d_in[14];
  const float* off_b  = (const float*)d_in[15];
  const float* attn_w = (const float*)d_in[16];
  const float* attn_b = (const float*)d_in[17];
  float* out = (float*)d_out;

  // workspace layout
  float* convall = (float*)d_ws;                    // 8*40000*24 = 7,680,000 f
  short* valpb  = (short*)(convall + 7680000);      // 16*40000*32 = 20,480,000 s
  short* img    = valpb + 20480000;                 // 203*202*512 = 20,996,672 s
  short* qbf    = img + 20996672;                   // 40000*256 = 10,240,000 s
  short* midb   = qbf + 10240000;                   // 40000*256 = 10,240,000 s
  short* wcat   = midb + 10240000;                  // 192*4608 = 884,736 s
  short* wvb    = wcat + 884736;                    // 65,536 s
  short* wob    = wvb + 65536;                      // 65,536 s
  float* bcat   = (float*)(wob + 65536);            // 192 f

  pad_kernel<<<dim3((203 * 202 * 64 + 255) / 256), dim3(256), 0, stream>>>(
      query, qpos, prebev, sos, img, qbf);
  reorder_cat_kernel<<<dim3((192 * 4608 + 255) / 256), dim3(256), 0, stream>>>(
      off_w, off_b, attn_w, attn_b, wcat, bcat);
  wcast_kernel<<<dim3(64), dim3(256), 0, stream>>>(Wv, Wo, wvb, wob);

  // valp(bf16 slabs) = val @ Wv^T + bv   (M=80000, N=256, K=256)
  mfma_gemm_kernel<A_VAL, 256, 128, 64, OUT_VSLAB>
      <<<dim3(625, 4), dim3(256), 0, stream>>>(
      img, qbf, wvb, bv, nullptr, nullptr, valpb, 2 * NQ);

  // merged convs (M=40000, N=192, K=4608) -> convall [h][n][24]
  mfma_gemm_kernel<A_IM2COL, 4608, 64, 192, OUT_CONV>
      <<<dim3(625, 1), dim3(256), 0, stream>>>(
      img, nullptr, wcat, bcat, nullptr, convall, nullptr, NQ);

  // softmax + bilinear sampling + queue average -> midb bf16
  sample_kernel<<<dim3(10000), dim3(256), 0, stream>>>(
      valpb, convall, preref, refp, midb);

  // out = mid @ Wo^T + bo + identity   (M=40000, N=256, K=256) -> fp32
  mfma_gemm_kernel<A_PLAIN, 256, 128, 64, OUT_F32ADD>
      <<<dim3(313, 4), dim3(256), 0, stream>>>(
      midb, nullptr, wob, bo, query, out, nullptr, NQ);

  (void)in_sizes; (void)n_in; (void)out_size; (void)ws_size;
}

// Round 8
// 462.464 us; speedup vs baseline: 1.1332x; 1.1332x over previous
//
#include <hip/hip_runtime.h>
#include <math.h>

#define NQ    40000
#define EDIM  256
#define BEVH  200
#define BEVW  200

enum { A_IM2COL = 0, A_VAL = 1, A_PLAIN = 2 };
enum { OUT_F32 = 0, OUT_VSLAB = 1, OUT_CONV = 2, OUT_F32ADD = 3 };

typedef __attribute__((ext_vector_type(8))) short bf16x8;
typedef __attribute__((ext_vector_type(4))) short bf16x4;
typedef __attribute__((ext_vector_type(4))) float f32x4;

typedef __attribute__((address_space(3))) unsigned int lds_u32_t;
typedef const __attribute__((address_space(1))) unsigned int g_u32_t;
#define GLOAD_LDS16(g, l) __builtin_amdgcn_global_load_lds((g_u32_t*)(g), (lds_u32_t*)(l), 16, 0, 0)

__device__ __forceinline__ short f2bf(float f) {
  union { float f; unsigned u; } uu; uu.f = f;
  unsigned r = (uu.u + 0x7fff + ((uu.u >> 16) & 1)) >> 16;
  return (short)r;
}
__device__ __forceinline__ float bf2f(short s) {
  union { unsigned u; float f; } v;
  v.u = ((unsigned)(unsigned short)s) << 16;
  return v.f;
}

// ---------------------------------------------------------------------------
// pad_kernel: zero-padded bf16 image img[203][202][512]; image (y,x) at padded
// (y+1,x+1). c<256 -> pre (= sos ? query : prebev); c>=256 -> query+qpos.
// Also writes qbf[n][0:256] = bf16(query).
// ---------------------------------------------------------------------------
__global__ __launch_bounds__(256) void pad_kernel(
    const float* __restrict__ query, const float* __restrict__ qpos,
    const float* __restrict__ prebev, const unsigned char* __restrict__ sos,
    short* __restrict__ img, short* __restrict__ qbf)
{
  const int TOT = 203 * 202 * 64;
  int t = blockIdx.x * 256 + threadIdx.x;
  if (t >= TOT) return;
  int s = t * 8;
  int pr = s / (202 * 512);
  int rem = s - pr * (202 * 512);
  int px = rem >> 9;
  int c = rem & 511;
  int y = pr - 1, x = px - 1;

  bf16x8 o;
#pragma unroll
  for (int j = 0; j < 8; j++) o[j] = 0;

  if (y >= 0 && y < BEVH && x >= 0 && x < BEVW) {
    int n = y * BEVW + x;
    if (c < 256) {
      bool sf = sos[0] != 0;
      const float* p = (sf ? query : prebev) + (size_t)n * 256 + c;
      float4 v0 = *(const float4*)p;
      float4 v1 = *(const float4*)(p + 4);
      o[0] = f2bf(v0.x); o[1] = f2bf(v0.y); o[2] = f2bf(v0.z); o[3] = f2bf(v0.w);
      o[4] = f2bf(v1.x); o[5] = f2bf(v1.y); o[6] = f2bf(v1.z); o[7] = f2bf(v1.w);
    } else {
      const float* pq = query + (size_t)n * 256 + (c - 256);
      const float* pp = qpos + (size_t)n * 256 + (c - 256);
      float4 q0 = *(const float4*)pq, q1 = *(const float4*)(pq + 4);
      float4 p0 = *(const float4*)pp, p1 = *(const float4*)(pp + 4);
      bf16x8 qo;
      qo[0] = f2bf(q0.x); qo[1] = f2bf(q0.y); qo[2] = f2bf(q0.z); qo[3] = f2bf(q0.w);
      qo[4] = f2bf(q1.x); qo[5] = f2bf(q1.y); qo[6] = f2bf(q1.z); qo[7] = f2bf(q1.w);
      *(bf16x8*)&qbf[(size_t)n * 256 + (c - 256)] = qo;
      o[0] = f2bf(q0.x + p0.x); o[1] = f2bf(q0.y + p0.y);
      o[2] = f2bf(q0.z + p0.z); o[3] = f2bf(q0.w + p0.w);
      o[4] = f2bf(q1.x + p1.x); o[5] = f2bf(q1.y + p1.y);
      o[6] = f2bf(q1.z + p1.z); o[7] = f2bf(q1.w + p1.w);
    }
  }
  *(bf16x8*)&img[s] = o;
}

// ---------------------------------------------------------------------------
// conv weights (co,ci,ky,kx) fp32 -> concat [192][tap*512+ci] bf16 + bias cat
// ---------------------------------------------------------------------------
__global__ __launch_bounds__(256) void reorder_cat_kernel(
    const float* __restrict__ off_w, const float* __restrict__ off_b,
    const float* __restrict__ attn_w, const float* __restrict__ attn_b,
    short* __restrict__ wcat, float* __restrict__ bcat)
{
  int i = blockIdx.x * 256 + threadIdx.x;
  if (i < 192) bcat[i] = i < 128 ? off_b[i] : attn_b[i - 128];
  if (i >= 192 * 4608) return;
  int co = i / 4608;
  int r = i - co * 4608;
  int tap = r >> 9, ci = r & 511;
  float v = co < 128 ? off_w[(size_t)co * 4608 + ci * 9 + tap]
                     : attn_w[(size_t)(co - 128) * 4608 + ci * 9 + tap];
  wcat[i] = f2bf(v);
}

__global__ __launch_bounds__(256) void wcast_kernel(
    const float* __restrict__ Wv, const float* __restrict__ Wo,
    short* __restrict__ wvb, short* __restrict__ wob)
{
  int t = blockIdx.x * 256 + threadIdx.x;
  if (t >= 16384) return;
  const float* src = t < 8192 ? Wv + (size_t)t * 8 : Wo + (size_t)(t - 8192) * 8;
  short* dst = t < 8192 ? wvb + (size_t)t * 8 : wob + (size_t)(t - 8192) * 8;
  float4 v0 = *(const float4*)src, v1 = *(const float4*)(src + 4);
  bf16x8 o;
  o[0] = f2bf(v0.x); o[1] = f2bf(v0.y); o[2] = f2bf(v0.z); o[3] = f2bf(v0.w);
  o[4] = f2bf(v1.x); o[5] = f2bf(v1.y); o[6] = f2bf(v1.z); o[7] = f2bf(v1.w);
  *(bf16x8*)dst = o;
}

// ---------------------------------------------------------------------------
// Unified bf16 MFMA GEMM: C[m][co] = sum_k A[m][k]*B[co][k] + bias[co]
// TBM x TBN tile, BK=64; 256 threads = 4 waves (2x2); wave tile TBM/2 x TBN/2.
// 1-phase K-loop (__syncthreads; proven) — TLP hides the vmcnt drain.
// IM2COL mode: grid is 1250 linear blocks; bijective XCD-chunk swizzle, then
// adjacent swizzled ids = (M-strip, N-half) pairs -> same XCD L2 shares the
// A window. (round-7 lesson: depth-1 dbuf pipelining cost occupancy & lost.)
// ---------------------------------------------------------------------------
template <int AMODE, int KTOT, int TBM, int TBN, int OUTMODE>
__global__ __launch_bounds__(256) void mfma_gemm_kernel(
    const short* __restrict__ A0, const short* __restrict__ A1,
    const short* __restrict__ Bw, const float* __restrict__ bias,
    const float* __restrict__ addend,
    float* __restrict__ Cf, short* __restrict__ Cb, int M)
{
  constexpr int A_ISS = TBM / 32;
  constexpr int B_ISS = TBN / 32;
  constexpr int MR = TBM / 32;     // frags per wave in M (wave M = TBM/2)
  constexpr int NR = TBN / 32;

  __shared__ __align__(16) short As[TBM * 64];
  __shared__ __align__(16) short Bs[TBN * 64];

  const int tid = threadIdx.x;
  const int wv = tid >> 6, lane = tid & 63;
  const int wr_ = wv >> 1, wc = wv & 1;

  int bx, n0;
  if constexpr (AMODE == A_IM2COL) {
    // nwg = 1250 = 625 strips x 2 N-halves. Bijective chunk swizzle (q=156,
    // r=2): xcd = id%8 gets chunk [base, base+len). Adjacent sids inside a
    // chunk are the two halves of one strip -> same XCD.
    int id = blockIdx.x;
    int xcd = id & 7, pos = id >> 3;
    int sid = (xcd < 2 ? xcd * 157 : 314 + (xcd - 2) * 156) + pos;
    bx = sid >> 1;
    n0 = (sid & 1) * TBN;
  } else {
    bx = blockIdx.x;
    n0 = blockIdx.y * TBN;
  }
  const int m0 = bx * TBM;

  // swizzle: LDS chunk j of row r holds global chunk j ^ (r & 7)
  const int csw = ((lane & 7) ^ ((lane >> 3) & 7)) * 8;

  const short* ap[A_ISS];
#pragma unroll
  for (int i = 0; i < A_ISS; i++) {
    int m = m0 + (i * 4 + wv) * 8 + (lane >> 3);
    if constexpr (AMODE == A_IM2COL) {
      int y = m / BEVW;
      int x = m - y * BEVW;
      ap[i] = A0 + ((size_t)y * 202 + x) * 512 + csw;   // + tap offset per K-tile
    } else if constexpr (AMODE == A_VAL) {
      if (m < NQ) {
        int y = m / BEVW;
        int x = m - y * BEVW;
        ap[i] = A0 + ((size_t)(y + 1) * 202 + (x + 1)) * 512 + csw;
      } else {
        ap[i] = A1 + (size_t)(m - NQ) * 256 + csw;
      }
    } else {
      int mc = m < M ? m : M - 1;
      ap[i] = A0 + (size_t)mc * KTOT + csw;
    }
  }
  const short* bp[B_ISS];
#pragma unroll
  for (int i = 0; i < B_ISS; i++) {
    int r = n0 + (i * 4 + wv) * 8 + (lane >> 3);
    bp[i] = Bw + (size_t)r * KTOT + csw;
  }

  f32x4 acc[MR][NR];
#pragma unroll
  for (int mr = 0; mr < MR; mr++)
#pragma unroll
    for (int nr = 0; nr < NR; nr++) acc[mr][nr] = (f32x4){0.f, 0.f, 0.f, 0.f};

  for (int k0 = 0; k0 < KTOT; k0 += 64) {
    int koff;
    if constexpr (AMODE == A_IM2COL) {
      int tap = k0 >> 9, c0 = k0 & 511;
      int ty = tap / 3, txp = tap - ty * 3;
      koff = (ty * 202 + txp) * 512 + c0;
    } else {
      koff = k0;
    }

#pragma unroll
    for (int i = 0; i < A_ISS; i++)
      GLOAD_LDS16(ap[i] + koff, &As[(i * 4 + wv) * 512]);
#pragma unroll
    for (int i = 0; i < B_ISS; i++)
      GLOAD_LDS16(bp[i] + k0, &Bs[(i * 4 + wv) * 512]);

    __syncthreads();

#pragma unroll
    for (int ks = 0; ks < 2; ks++) {
      const int kk = ks * 32 + (lane >> 4) * 8;
      bf16x8 af[MR], bfr[NR];
#pragma unroll
      for (int mr = 0; mr < MR; mr++) {
        int row = wr_ * (TBM / 2) + mr * 16 + (lane & 15);
        af[mr] = *(const bf16x8*)&As[row * 64 + (kk ^ ((row & 7) << 3))];
      }
#pragma unroll
      for (int nr = 0; nr < NR; nr++) {
        int row = wc * (TBN / 2) + nr * 16 + (lane & 15);
        bfr[nr] = *(const bf16x8*)&Bs[row * 64 + (kk ^ ((row & 7) << 3))];
      }
#pragma unroll
      for (int mr = 0; mr < MR; mr++)
#pragma unroll
        for (int nr = 0; nr < NR; nr++)
          acc[mr][nr] = __builtin_amdgcn_mfma_f32_16x16x32_bf16(
              af[mr], bfr[nr], acc[mr][nr], 0, 0, 0);
    }
    __syncthreads();
  }

  // epilogue: C/D layout col=lane&15, row=(lane>>4)*4+reg
#pragma unroll
  for (int mr = 0; mr < MR; mr++) {
#pragma unroll
    for (int nr = 0; nr < NR; nr++) {
      int col = n0 + wc * (TBN / 2) + nr * 16 + (lane & 15);
      float bsv = bias[col];
#pragma unroll
      for (int r = 0; r < 4; r++) {
        int grow = m0 + wr_ * (TBM / 2) + mr * 16 + (lane >> 4) * 4 + r;
        if (grow < M) {
          float o = acc[mr][nr][r] + bsv;
          if constexpr (OUTMODE == OUT_VSLAB) {
            int b = grow >= NQ;
            int n = grow - (b ? NQ : 0);
            int hh = col >> 5, d = col & 31;
            Cb[((size_t)(hh * 2 + b) * NQ + n) * 32 + d] = f2bf(o);
          } else if constexpr (OUTMODE == OUT_CONV) {
            int hh, j;
            if (col < 128) { hh = col >> 4; j = col & 15; }
            else { int c = col - 128; hh = c >> 3; j = 16 + (c & 7); }
            Cf[((size_t)hh * NQ + grow) * 24 + j] = o;
          } else if constexpr (OUTMODE == OUT_F32ADD) {
            o += addend[(size_t)grow * 256 + col];
            Cf[(size_t)grow * 256 + col] = o;
          } else {
            Cf[(size_t)grow * 256 + col] = o;
          }
        }
      }
    }
  }
}

// ---------------------------------------------------------------------------
// sample v3: blockIdx = q*8 + h  (h pins the block's XCD via id%8 heuristic:
// each XCD's random gathers touch only head h's 5.1 MB valp slab -> L2-hot).
// Wave: 8 queries x 8 lanes; lane g covers channels g*4..g*4+3 of head h.
// convall: [h][n][24] = {offsets b0 (8), offsets b1 (8), logits b0 (4), b1 (4)}
// valpb:   [(h*2+b)][n][32]
// ---------------------------------------------------------------------------
__global__ __launch_bounds__(256) void sample_kernel(
    const short* __restrict__ valpb, const float* __restrict__ convall,
    const float* __restrict__ preref, const float* __restrict__ refp,
    short* __restrict__ midb)
{
  int id = blockIdx.x;
  int h = id & 7, q = id >> 3;
  int wv = threadIdx.x >> 6, lane = threadIdx.x & 63;
  int n = q * 32 + wv * 8 + (lane >> 3);
  int g = lane & 7;

  const float* cv = convall + ((size_t)h * NQ + n) * 24;
  f32x4 acc = (f32x4){0.f, 0.f, 0.f, 0.f};

#pragma unroll
  for (int b = 0; b < 2; b++) {
    const float* rp = b ? refp : preref;
    float rx = rp[(size_t)n * 2 + 0] * 200.f - 0.5f;
    float ry = rp[(size_t)n * 2 + 1] * 200.f - 0.5f;

    float4 o01 = *(const float4*)(cv + b * 8);
    float4 o23 = *(const float4*)(cv + b * 8 + 4);
    float ox[4] = {o01.x, o01.z, o23.x, o23.z};
    float oy[4] = {o01.y, o01.w, o23.y, o23.w};

    float4 a = *(const float4*)(cv + 16 + b * 4);
    float mx = fmaxf(fmaxf(a.x, a.y), fmaxf(a.z, a.w));
    float e0 = __expf(a.x - mx), e1 = __expf(a.y - mx);
    float e2 = __expf(a.z - mx), e3 = __expf(a.w - mx);
    float inv = 1.f / (e0 + e1 + e2 + e3);
    float aw[4] = {e0 * inv, e1 * inv, e2 * inv, e3 * inv};

    const short* vb = valpb + ((size_t)(h * 2 + b) * NQ) * 32 + g * 4;

#pragma unroll
    for (int p = 0; p < 4; p++) {
      float x = rx + ox[p];
      float y = ry + oy[p];
      float x0f = floorf(x), y0f = floorf(y);
      float fx = x - x0f, fy = y - y0f;
      int x0 = (int)x0f, y0 = (int)y0f;
      float wt[4] = {(1.f - fx) * (1.f - fy), fx * (1.f - fy),
                     (1.f - fx) * fy, fx * fy};
      int xs[4] = {x0, x0 + 1, x0, x0 + 1};
      int ys[4] = {y0, y0, y0 + 1, y0 + 1};
#pragma unroll
      for (int c = 0; c < 4; c++) {
        if (xs[c] >= 0 && xs[c] < BEVW && ys[c] >= 0 && ys[c] < BEVH) {
          bf16x4 v = *(const bf16x4*)&vb[(size_t)(ys[c] * BEVW + xs[c]) * 32];
          float cw = aw[p] * wt[c];
          acc[0] += cw * bf2f(v[0]);
          acc[1] += cw * bf2f(v[1]);
          acc[2] += cw * bf2f(v[2]);
          acc[3] += cw * bf2f(v[3]);
        }
      }
    }
  }

  bf16x4 m4;
#pragma unroll
  for (int j = 0; j < 4; j++) m4[j] = f2bf(acc[j] * 0.5f);
  *(bf16x4*)&midb[(size_t)n * 256 + h * 32 + g * 4] = m4;
}

// ---------------------------------------------------------------------------
extern "C" void kernel_launch(void* const* d_in, const int* in_sizes, int n_in,
                              void* d_out, int out_size, void* d_ws, size_t ws_size,
                              hipStream_t stream)
{
  const float* query  = (const float*)d_in[0];
  const float* qpos   = (const float*)d_in[3];
  const float* refp   = (const float*)d_in[4];
  const float* prebev = (const float*)d_in[7];
  const float* preref = (const float*)d_in[8];
  const unsigned char* sos = (const unsigned char*)d_in[9];
  const float* Wv     = (const float*)d_in[10];
  const float* bv     = (const float*)d_in[11];
  const float* Wo     = (const float*)d_in[12];
  const float* bo     = (const float*)d_in[13];
  const float* off_w  = (const float*)d_in[14];
  const float* off_b  = (const float*)d_in[15];
  const float* attn_w = (const float*)d_in[16];
  const float* attn_b = (const float*)d_in[17];
  float* out = (float*)d_out;

  // workspace layout
  float* convall = (float*)d_ws;                    // 8*40000*24 = 7,680,000 f
  short* valpb  = (short*)(convall + 7680000);      // 16*40000*32 = 20,480,000 s
  short* img    = valpb + 20480000;                 // 203*202*512 = 20,996,672 s
  short* qbf    = img + 20996672;                   // 40000*256 = 10,240,000 s
  short* midb   = qbf + 10240000;                   // 40000*256 = 10,240,000 s
  short* wcat   = midb + 10240000;                  // 192*4608 = 884,736 s
  short* wvb    = wcat + 884736;                    // 65,536 s
  short* wob    = wvb + 65536;                      // 65,536 s
  float* bcat   = (float*)(wob + 65536);            // 192 f

  pad_kernel<<<dim3((203 * 202 * 64 + 255) / 256), dim3(256), 0, stream>>>(
      query, qpos, prebev, sos, img, qbf);
  reorder_cat_kernel<<<dim3((192 * 4608 + 255) / 256), dim3(256), 0, stream>>>(
      off_w, off_b, attn_w, attn_b, wcat, bcat);
  wcast_kernel<<<dim3(64), dim3(256), 0, stream>>>(Wv, Wo, wvb, wob);

  // valp(bf16 slabs) = val @ Wv^T + bv   (M=80000, N=256, K=256)
  mfma_gemm_kernel<A_VAL, 256, 128, 64, OUT_VSLAB>
      <<<dim3(625, 4), dim3(256), 0, stream>>>(
      img, qbf, wvb, bv, nullptr, nullptr, valpb, 2 * NQ);

  // merged convs (M=40000, N=192, K=4608) -> convall [h][n][24]
  // 1250 blocks = 625 M-strips x 2 N-halves, XCD-paired
  mfma_gemm_kernel<A_IM2COL, 4608, 64, 96, OUT_CONV>
      <<<dim3(1250, 1), dim3(256), 0, stream>>>(
      img, nullptr, wcat, bcat, nullptr, convall, nullptr, NQ);

  // softmax + bilinear sampling + queue average -> midb bf16
  sample_kernel<<<dim3(10000), dim3(256), 0, stream>>>(
      valpb, convall, preref, refp, midb);

  // out = mid @ Wo^T + bo + identity   (M=40000, N=256, K=256) -> fp32
  mfma_gemm_kernel<A_PLAIN, 256, 128, 64, OUT_F32ADD>
      <<<dim3(313, 4), dim3(256), 0, stream>>>(
      midb, nullptr, wob, bo, query, out, nullptr, NQ);

  (void)in_sizes; (void)n_in; (void)out_size; (void)ws_size;
}